// Round 1
// baseline (463.886 us; speedup 1.0000x reference)
//
#include <hip/hip_runtime.h>

// segments: (8, 1, 512, 512) f32, values 0..63; downsample ::2 -> (8, 256, 256)
// R=7, K_SIDE=15, 225 offsets, zero-padded OOB neighbors
// out: (8, 225, 256, 256) f32 = 471.9 MB  -> write-BW floor ~75 us
//
// R3: plane-major decomposition. Previous version wrote 1 KB chunks at 256 KB
// stride (all 225 planes from one y-row block) -> DRAM row-buffer thrash,
// 1.02 TB/s effective (fillBuffer hits 6.3 TB/s on the same buffer).
// Now: each block owns one (b, plane, 64-row chunk) and streams a CONTIGUOUS
// 64 KB of output, like the fill kernel. Plane p=(dy,dx) is just an
// elementwise compare of seg with a shifted copy of itself.
// Pre-pass downsamples+zero-pads seg into ws (2.35 MB, L2-resident):
//   ws[b][yy][xx], yy = gy+7 (rows 0..269), xx = gx+8 (cols, pitch 272)
//   8-col left pad keeps the "own" float4 load 16B-aligned.

#define RAD 7
#define KS 15
#define HW 256
#define IN_W 512
#define PLANE (HW * HW)          // 65536
#define WSROWS 270               // 256 + 2*RAD
#define WSPITCH 272              // 8 left pad + 256 + 8 right pad (16B-aligned rows)
#define WSPLANE (WSROWS * WSPITCH)
#define WS_BYTES ((size_t)8 * WSPLANE * 4)   // 2,350,080 B

typedef float vf4 __attribute__((ext_vector_type(4)));

__global__ __launch_bounds__(256) void downsample_pad(const float* __restrict__ in,
                                                      float* __restrict__ ws) {
    int t = blockIdx.x * 256 + threadIdx.x;
    const int N = 8 * WSPLANE;
    if (t >= N) return;
    int xx   = t % WSPITCH;
    int rest = t / WSPITCH;
    int yy   = rest % WSROWS;
    int b    = rest / WSROWS;
    int gy = yy - RAD;   // downsampled row
    int gx = xx - 8;     // downsampled col
    float v = 0.0f;
    if ((unsigned)gy < HW && (unsigned)gx < HW) {
        v = in[(size_t)b * (IN_W * IN_W) + (size_t)(2 * gy) * IN_W + 2 * gx];
    }
    ws[t] = v;
}

// grid: (225*4, 8). bx = p*4 + ychunk; each block writes 64 contiguous rows
// (64 KB) of one plane. 4 waves interleave rows y0+wv, +4, ... so the block's
// store stream advances linearly through its 64 KB region.
__global__ __launch_bounds__(256) void adj_planes(const float* __restrict__ ws,
                                                  float* __restrict__ out) {
    const int bx = blockIdx.x;
    const int p  = bx >> 2;              // 0..224
    const int y0 = (bx & 3) * 64;
    const int b  = blockIdx.y;
    const int dy = p / KS;               // 0..14
    const int dx = p - dy * KS;          // 0..14

    const int tid  = threadIdx.x;
    const int wv   = tid >> 6;
    const int lane = tid & 63;
    const int x    = lane * 4;

    const float* wsb = ws + (size_t)b * WSPLANE;
    float* ob = out + ((size_t)(b * (KS * KS) + p)) * PLANE
                    + (size_t)y0 * HW + x;

    for (int yi = wv; yi < 64; yi += 4) {
        const int y = y0 + yi;
        // own segment ids: aligned float4 (xx = 8 + x)
        const vf4 own = *(const vf4*)(wsb + (size_t)(y + RAD) * WSPITCH + 8 + x);
        // neighbor: row y+dy-7 -> yy = y+dy; col x+k+dx-7 -> xx = x+dx+1+k
        const float* np = wsb + (size_t)(y + dy) * WSPITCH + (x + dx + 1);
        const float n0 = np[0], n1 = np[1], n2 = np[2], n3 = np[3];
        vf4 v;
        v.x = (own.x == n0) ? 1.0f : 0.0f;
        v.y = (own.y == n1) ? 1.0f : 0.0f;
        v.z = (own.z == n2) ? 1.0f : 0.0f;
        v.w = (own.w == n3) ? 1.0f : 0.0f;
        __builtin_nontemporal_store(v, (vf4*)(ob + (size_t)yi * HW));
    }
}

// Fallback if the provided workspace is too small: same decomposition, reads
// straight from the full-res input with bounds checks (L2/L3-resident).
__global__ __launch_bounds__(256) void adj_planes_direct(const float* __restrict__ in,
                                                         float* __restrict__ out) {
    const int bx = blockIdx.x;
    const int p  = bx >> 2;
    const int y0 = (bx & 3) * 64;
    const int b  = blockIdx.y;
    const int dy = p / KS;
    const int dx = p - dy * KS;

    const int tid  = threadIdx.x;
    const int wv   = tid >> 6;
    const int lane = tid & 63;
    const int x    = lane * 4;

    const float* inb = in + (size_t)b * (IN_W * IN_W);
    float* ob = out + ((size_t)(b * (KS * KS) + p)) * PLANE
                    + (size_t)y0 * HW + x;

    for (int yi = wv; yi < 64; yi += 4) {
        const int y  = y0 + yi;
        const int ny = y + dy - RAD;
        const bool yok = (unsigned)ny < HW;
        const float* own_row = inb + (size_t)(2 * y) * IN_W;
        const float* nb_row  = inb + (size_t)(2 * (yok ? ny : 0)) * IN_W;
        vf4 v;
        #pragma unroll
        for (int k = 0; k < 4; ++k) {
            const float s = own_row[2 * (x + k)];
            const int nx = x + k + dx - RAD;
            float n = 0.0f;
            if (yok && (unsigned)nx < HW) n = nb_row[2 * nx];
            const float r = (s == n) ? 1.0f : 0.0f;
            if (k == 0) v.x = r; else if (k == 1) v.y = r;
            else if (k == 2) v.z = r; else v.w = r;
        }
        __builtin_nontemporal_store(v, (vf4*)(ob + (size_t)yi * HW));
    }
}

extern "C" void kernel_launch(void* const* d_in, const int* in_sizes, int n_in,
                              void* d_out, int out_size, void* d_ws, size_t ws_size,
                              hipStream_t stream) {
    const float* segments = (const float*)d_in[0];
    float* out = (float*)d_out;

    if (d_ws != nullptr && ws_size >= WS_BYTES) {
        float* ws = (float*)d_ws;
        const int N = 8 * WSPLANE;
        downsample_pad<<<dim3((N + 255) / 256), dim3(256), 0, stream>>>(segments, ws);
        adj_planes<<<dim3(KS * KS * 4, 8), dim3(256), 0, stream>>>(ws, out);
    } else {
        adj_planes_direct<<<dim3(KS * KS * 4, 8), dim3(256), 0, stream>>>(segments, out);
    }
}